// Round 1
// baseline (358.829 us; speedup 1.0000x reference)
//
#include <hip/hip_runtime.h>

#define NUM_GRAPHS 1024
#define F_DIM 512

// Workspace layout: A[g*8 + j] for j=0..6 = per-graph feature-dot sums,
// A[g*8 + 7] = node count for graph g. Total 1024*8 floats = 32 KB.

__global__ void zero_ws_kernel(float* __restrict__ A, int n) {
    int i = blockIdx.x * blockDim.x + threadIdx.x;
    if (i < n) A[i] = 0.0f;
}

__device__ __forceinline__ void flush_segment(const float (&acc)[7], int seg_cnt,
                                              int g, int lane, int half_id,
                                              float* __restrict__ A) {
    #pragma unroll
    for (int j = 0; j < 7; ++j) {
        float v = acc[j];
        #pragma unroll
        for (int off = 32; off > 0; off >>= 1)
            v += __shfl_down(v, off, 64);
        if (lane == 0) atomicAdd(A + g * 8 + j, v);
    }
    // Each chunk is covered by TWO waves (feature halves); only half 0 counts nodes.
    if (lane == 0 && half_id == 0) atomicAdd(A + g * 8 + 7, (float)seg_cnt);
}

// Two waves per contiguous chunk of K<=64 nodes: wave pair (chunk, half).
// Lane l of half h owns the contiguous float4 at features [h*256 + 4l, +4).
// Every wave-load is a fully-coalesced contiguous 1024 B segment (16 cachelines,
// all bytes used) — vs the previous stride-32B mapping that touched 32 lines per
// load using half of each. W fragment is 28 VGPRs (was 56) so the kernel fits
// 8 waves/SIMD (launch_bounds 256,8 -> 32 waves/CU), doubling latency hiding.
__global__ __launch_bounds__(256, 8) void node_accum_kernel(
        const float* __restrict__ x, const int* __restrict__ batch,
        const float* __restrict__ W, float* __restrict__ A, int N) {
    const int lane = threadIdx.x & 63;
    const int wave = (blockIdx.x * blockDim.x + threadIdx.x) >> 6;
    const int chunk = wave >> 1;            // 4096 chunks
    const int half_id = wave & 1;           // which 256-feature half
    const int num_chunks = (gridDim.x * blockDim.x) >> 7;
    const int K = (N + num_chunks - 1) / num_chunks;   // 25 for N=100000
    const int start = chunk * K;
    const int len = min(N - start, K);
    if (len <= 0) return;

    const int foff = half_id * (F_DIM / 2) + lane * 4;

    // W fragment in registers: lane holds W[j][foff .. foff+4) for j=0..6
    float4 w[7];
    #pragma unroll
    for (int j = 0; j < 7; ++j)
        w[j] = *(const float4*)(W + j * F_DIM + foff);

    // One coalesced load of the chunk's batch ids (lanes >= len clamp to last).
    int g_l = batch[start + min(lane, len - 1)];
    int g_prev = __shfl_up(g_l, 1, 64);
    unsigned long long bnd =
        __ballot(lane > 0 && lane < len && g_l != g_prev);  // start-of-new-segment lanes

    int s = 0;
    while (s < len) {
        const int g = __shfl(g_l, s, 64);
        // next boundary strictly after s, else len
        unsigned long long m = (s < 63) ? (bnd & (~0ULL << (s + 1))) : 0ULL;
        int e = m ? (__ffsll((long long)m) - 1) : len;

        float acc[7];
        #pragma unroll
        for (int j = 0; j < 7; ++j) acc[j] = 0.0f;

        const int n = e - s;
        const float* xb = x + (size_t)(start + s) * F_DIM + foff;
        // software pipeline: next node's load in flight during current FMAs
        float4 a = *(const float4*)xb;
        for (int t = 1; t < n; ++t) {
            float4 na = *(const float4*)(xb + (size_t)t * F_DIM);
            #pragma unroll
            for (int j = 0; j < 7; ++j)
                acc[j] += a.x * w[j].x + a.y * w[j].y + a.z * w[j].z + a.w * w[j].w;
            a = na;
        }
        #pragma unroll
        for (int j = 0; j < 7; ++j)
            acc[j] += a.x * w[j].x + a.y * w[j].y + a.z * w[j].z + a.w * w[j].w;

        flush_segment(acc, n, g, lane, half_id, A);
        s = e;
    }
}

__global__ void finalize_kernel(const float* __restrict__ A,
                                const float* __restrict__ b,
                                float* __restrict__ out) {
    int idx = blockIdx.x * blockDim.x + threadIdx.x;
    if (idx >= NUM_GRAPHS * 7) return;
    int g = idx / 7;
    int j = idx - g * 7;
    float cnt = A[g * 8 + 7];
    out[idx] = A[g * 8 + j] / fmaxf(cnt, 1.0f) + b[j];
}

extern "C" void kernel_launch(void* const* d_in, const int* in_sizes, int n_in,
                              void* d_out, int out_size, void* d_ws, size_t ws_size,
                              hipStream_t stream) {
    // Input order: x[100000,512] f32, edge_index (UNUSED), edge_attr (UNUSED),
    // batch_size[100000] int, W[7,512] f32, b[7] f32.
    const float* x     = (const float*)d_in[0];
    const int*   batch = (const int*)d_in[3];
    const float* W     = (const float*)d_in[4];
    const float* b     = (const float*)d_in[5];
    float* out = (float*)d_out;
    float* A   = (float*)d_ws;           // 1024*8 floats = 32 KB
    const int N = in_sizes[3];           // 100000 nodes

    const int ws_elems = NUM_GRAPHS * 8;
    zero_ws_kernel<<<(ws_elems + 255) / 256, 256, 0, stream>>>(A, ws_elems);

    // 2048 blocks * 256 thr = 8192 waves = 2 waves (feature halves) per chunk,
    // 4096 chunks of 25 contiguous nodes. 8 blocks/CU -> full 32 waves/CU.
    node_accum_kernel<<<2048, 256, 0, stream>>>(x, batch, W, A, N);

    finalize_kernel<<<(NUM_GRAPHS * 7 + 255) / 256, 256, 0, stream>>>(A, b, out);
}